// Round 4
// baseline (1475.345 us; speedup 1.0000x reference)
//
#include <hip/hip_runtime.h>

// Multi-layer tanh RNN, layer-pipelined persistent kernel.
// R20 = R19 (A-hoist, split chains, K=8/RD=32) + two VMEM fixes:
//  (a) bf16 ring in padded-LDS layout (slot = BC*HSS*2 = 4352B):
//      producer stores the ring slot from hbuf LDS as contiguous 16B chunks
//      -> coalesced dwordx4 stores (~64 L2 txns vs ~2048 scattered 4B), and
//      consumer staging is a pure chunk copy (pack4 VALU eliminated).
//      Bit-identical numerics: ring carries the same bf16 RTN values.
//  (b) prefetch distance 2 (pA/pB queue): slot t+2 issued at step t, staged
//      at t+1 -> >=1.5 steps in flight; the per-step vmcnt drain before the
//      ibuf ds_write (R16/R19: distance-1, ~1 partial step vs ~900cyc HBM
//      miss, FETCH 448MB showed half the ring reads miss) leaves the
//      critical path.
//  R19 lesson: K=8 fill win (-150us) was eaten by pricier boundaries; with
//  (a)+(b) boundaries are cheap, so the fill win should materialize.
// Protocol, precision, MFMA structure unchanged from R16/R19. 2 blk/CU.

#define HH   100   // hidden
#define HS   132   // padded fp32 stride (bias etc.)
#define HSS  136   // bf16 LDS row stride in shorts (272B = 17*16, b128-aligned)
#define NL   10    // layers
#define BBS  512   // batch
#define TTS  512   // time
#define NB   32    // batch chunks
#define BC   16    // batch per chunk
#define NT   256   // threads per block
#define SLOTB (BC * HSS * 2)   // 4352 bytes per bf16 ring slot

typedef __attribute__((ext_vector_type(8))) short short8;
typedef __attribute__((ext_vector_type(4))) float f32x4;
typedef __attribute__((ext_vector_type(2))) unsigned int u32x2;
typedef __attribute__((ext_vector_type(4))) unsigned int u32x4;

__global__ void init_ws_kernel(int* wsi) {
  int i = blockIdx.x * blockDim.x + threadIdx.x;
  if (i < 16384) wsi[i] = 0;   // zero both flag regions (64KB)
}

__device__ __forceinline__ int flag_idx(int iface, int chunk) {
  return (iface * NB + chunk) * 16;
}

__device__ __forceinline__ void lds_barrier() {
  __asm__ __volatile__("s_waitcnt lgkmcnt(0)\n\ts_barrier" ::: "memory");
}
__device__ __forceinline__ void ctl_barrier() {
  __asm__ __volatile__("s_barrier" ::: "memory");
}

__device__ __forceinline__ float fast_tanh(float v) {
  float e = __expf(2.0f * v);
  return 1.0f - 2.0f * __builtin_amdgcn_rcpf(e + 1.0f);
}

__device__ __forceinline__ unsigned short bf_rtn(float x) {
  return (unsigned short)((__float_as_uint(x) + 0x8000u) >> 16);
}

__global__ __launch_bounds__(NT, 2) void rnn_pipe(
    const float* __restrict__ x,     // [B,T,1]
    const float* __restrict__ h0,    // [L,B,H]
    const float* __restrict__ Wih0,  // [H,1]
    const float* __restrict__ Wih,   // [L-1,H,H]
    const float* __restrict__ Whh,   // [L,H,H]
    const float* __restrict__ bih,   // [L,H]
    const float* __restrict__ bhh,   // [L,H]
    const float* __restrict__ Wout,  // [1,H]
    const float* __restrict__ bout,  // [1]
    float* __restrict__ out,         // [B*T] outs ++ [L*B*H] h_final
    unsigned char* __restrict__ ring,
    int*   __restrict__ wsi,
    int Kv, int RDv)
{
  const int layer = blockIdx.x / NB;
  const int chunk = blockIdx.x % NB;
  const int tid   = threadIdx.x;
  const int Km = Kv - 1, RDm = RDv - 1;
  const int NE = BC * HH;  // 1600 elements per activation slot

  const int wave = tid >> 6, lane = tid & 63;
  const int quad = lane >> 4, lp = lane & 15;

  // LDS: 4*16*136*2 = 17.4KB state + ~1.7KB consts
  __shared__ unsigned short hbuf[2][BC][HSS];  // recurrent state bf16
  __shared__ unsigned short ibuf[2][BC][HSS];  // staged prev-layer input bf16
  __shared__ float bias[HS];
  __shared__ float wi0s[HS];
  __shared__ float wouts[HS];
  __shared__ float xin[2][BC];

  // ---- one-time LDS init ----
  for (int i = tid; i < 2 * BC * HSS; i += NT) {
    (&hbuf[0][0][0])[i] = 0; (&ibuf[0][0][0])[i] = 0;
  }
  for (int i = tid; i < HS; i += NT) {
    bias[i]  = (i < HH) ? (bih[layer * HH + i] + bhh[layer * HH + i]) : 0.f;
    wi0s[i]  = (i < HH) ? Wih0[i] : 0.f;
    wouts[i] = (i < HH) ? Wout[i] : 0.f;
  }
  if (tid < BC) { xin[0][tid] = 0.f; xin[1][tid] = 0.f; }
  __syncthreads();
  for (int idx = tid; idx < NE; idx += NT)
    hbuf[0][idx / HH][idx % HH] =
        bf_rtn(h0[((size_t)layer * BBS + chunk * BC + idx / HH) * HH + idx % HH]);
  __syncthreads();

  // ---- B-fragments in registers: fused W = [Whh (k 0..99) ; Wih (k 128..227)]
  // 2-plane (weight precision kept), 128 regs.
  short8 Bf[8][2][2];
  #pragma unroll
  for (int kc = 0; kc < 8; ++kc) {
    #pragma unroll
    for (int ntl = 0; ntl < 2; ++ntl) {
      const int n = wave * 32 + ntl * 16 + lp;
      float wv[8];
      #pragma unroll
      for (int j = 0; j < 8; ++j) {
        const int k = kc * 32 + quad * 8 + j;
        float w = 0.f;
        if (kc < 4) {
          if (k < HH && n < HH) w = Whh[(size_t)layer * HH * HH + n * HH + k];
        } else {
          const int kk = k - 128;
          if (layer > 0 && kk >= 0 && kk < HH && n < HH)
            w = Wih[(size_t)(layer - 1) * HH * HH + n * HH + kk];
        }
        wv[j] = w;
      }
      // plane1 = truncate, plane2 = residual (exact split)
      __attribute__((ext_vector_type(4))) unsigned int p1, p2;
      #pragma unroll
      for (int j2 = 0; j2 < 4; ++j2) {
        unsigned ua = __float_as_uint(wv[2 * j2]), ub = __float_as_uint(wv[2 * j2 + 1]);
        p1[j2] = (ua >> 16) | (ub & 0xFFFF0000u);
        float ra = wv[2 * j2]     - __uint_as_float(ua & 0xFFFF0000u);
        float rb = wv[2 * j2 + 1] - __uint_as_float(ub & 0xFFFF0000u);
        p2[j2] = (__float_as_uint(ra) >> 16) | (__float_as_uint(rb) & 0xFFFF0000u);
      }
      Bf[kc][ntl][0] = __builtin_bit_cast(short8, p1);
      Bf[kc][ntl][1] = __builtin_bit_cast(short8, p2);
    }
  }

  // ---- flags / ring pointers (R8-proven protocol, agent scope) ----
  int* prog_in  = (layer > 0)      ? wsi + flag_idx(layer - 1, chunk)        : nullptr;
  int* cons_in  = (layer > 0)      ? wsi + 8192 + flag_idx(layer - 1, chunk) : nullptr;
  int* prog_out = (layer < NL - 1) ? wsi + flag_idx(layer, chunk)            : nullptr;
  int* cons_out = (layer < NL - 1) ? wsi + 8192 + flag_idx(layer, chunk)     : nullptr;
  unsigned char* ring_in  = (layer > 0)
      ? ring + (size_t)((layer - 1) * NB + chunk) * RDv * SLOTB : nullptr;
  unsigned char* ring_out = (layer < NL - 1)
      ? ring + (size_t)(layer * NB + chunk) * RDv * SLOTB       : nullptr;

  const int jcv[2] = { wave * 32 + lp, wave * 32 + 16 + lp };   // C columns
  const float br[2]  = { bias[jcv[0]], bias[jcv[1]] };
  const float w0r[2] = { wi0s[jcv[0]], wi0s[jcv[1]] };
  const float boutv = bout[0];

  f32x4 hreg[2];             // step-t h values fp32 (h_final exactness)
  float dso = 0.f;           // deferred layer-9 output
  float px = 0.f;
  u32x4 pA0 = {}, pA1 = {};  // prefetch queue head: slot t+1 chunks
  bool have_out_def = false;

  const int co0 = tid * 16;          // chunk byte offset 0..4095
  const int co1 = 4096 + tid * 16;   // tail chunk for tid<16 (4096..4351)

  for (int t = 0; t < TTS; ++t) {
    const int par = t & 1, nxt = par ^ 1;
    const bool batch_start = (t & Km) == 0;
    const bool batch_last  = (t & Km) == Km;
    const int batch_end = t | Km;    // last slot index of current batch

    char* ibase = (char*)&ibuf[par][0][0];
    char* inext = (char*)&ibuf[nxt][0][0];
    char* hbase = (char*)&hbuf[par][0][0];
    char* hnext = (char*)&hbuf[nxt][0][0];

    // ---- batch boundary: wait + exposed chunk-copy of slot t ----
    if (batch_start) {
      if (tid == 0) {
        if (layer > 0) {
          while (__hip_atomic_load(prog_in, __ATOMIC_RELAXED, __HIP_MEMORY_SCOPE_AGENT) < t + Kv)
            __builtin_amdgcn_s_sleep(1);
          (void)__hip_atomic_load(prog_in, __ATOMIC_ACQUIRE, __HIP_MEMORY_SCOPE_AGENT);
        }
        if (layer < NL - 1 && t + Kv > RDv) {
          while (__hip_atomic_load(cons_out, __ATOMIC_RELAXED, __HIP_MEMORY_SCOPE_AGENT) < t + Kv - RDv)
            __builtin_amdgcn_s_sleep(1);
        }
      }
      ctl_barrier();
      if (layer > 0) {
        const char* srcb = (const char*)(ring_in + (size_t)(t & RDm) * SLOTB);
        u32x4 g0 = *(const u32x4*)(srcb + co0);
        u32x4 g1 = {};
        if (tid < 16) g1 = *(const u32x4*)(srcb + co1);
        *(u32x4*)(ibase + co0) = g0;
        if (tid < 16) *(u32x4*)(ibase + co1) = g1;
      } else if (t == 0) {
        if (tid < BC) xin[0][tid] = x[(size_t)(chunk * BC + tid) * TTS];
      }
      lds_barrier();
    }

    // ---- deferred ring store of slot t-1, sourced from hbuf[par] (LDS) ----
    // (coalesced 16B chunks; skipped at batch_start: slot t-1 was the
    //  batch_last slot, already stored+published last step)
    if (layer < NL - 1 && t > 0 && !batch_start) {
      char* dstb = (char*)(ring_out + (size_t)((t - 1) & RDm) * SLOTB);
      u32x4 h0v = *(const u32x4*)(hbase + co0);
      u32x4 h1v = {};
      if (tid < 16) h1v = *(const u32x4*)(hbase + co1);
      *(u32x4*)(dstb + co0) = h0v;
      if (tid < 16) *(u32x4*)(dstb + co1) = h1v;
    }
    if (have_out_def) {
      if ((tid & 15) == 0)
        out[(size_t)(chunk * BC + (tid >> 4)) * TTS + (t - 1)] = dso;
      have_out_def = false;
    }

    // ---- prefetch queue: refill head at boundary, issue slot t+2 -> pB ----
    u32x4 pB0 = {}, pB1 = {};
    if (layer > 0) {
      if (batch_start && t + 1 <= batch_end) {
        const char* s1 = (const char*)(ring_in + (size_t)((t + 1) & RDm) * SLOTB);
        pA0 = *(const u32x4*)(s1 + co0);
        if (tid < 16) pA1 = *(const u32x4*)(s1 + co1);
      }
      if (t + 2 <= batch_end) {
        const char* s2 = (const char*)(ring_in + (size_t)((t + 2) & RDm) * SLOTB);
        pB0 = *(const u32x4*)(s2 + co0);
        if (tid < 16) pB1 = *(const u32x4*)(s2 + co1);
      }
    } else {
      if (t + 1 < TTS && tid < BC) px = x[(size_t)(chunk * BC + tid) * TTS + (t + 1)];
    }

    // ---- A-fragments: hoist ALL LDS reads ahead of MFMAs ----
    short8 Ah[4], Ai[4];
    #pragma unroll
    for (int kc = 0; kc < 4; ++kc)
      Ah[kc] = *(const short8*)&hbuf[par][lp][kc * 32 + quad * 8];
    if (layer > 0) {
      #pragma unroll
      for (int kc = 0; kc < 4; ++kc)
        Ai[kc] = *(const short8*)&ibuf[par][lp][kc * 32 + quad * 8];
    } else {
      #pragma unroll
      for (int kc = 0; kc < 4; ++kc) Ai[kc] = short8{};
    }

    // ---- MFMA: split per-plane chains (4-deep each), merged by VALU adds ----
    f32x4 a1[2] = {}, a2[2] = {};   // hbuf part: plane1 / plane2 chains
    f32x4 c1[2] = {}, c2[2] = {};   // ibuf part
    #pragma unroll
    for (int kc = 0; kc < 4; ++kc) {
      #pragma unroll
      for (int ntl = 0; ntl < 2; ++ntl) {
        a2[ntl] = __builtin_amdgcn_mfma_f32_16x16x32_bf16(Ah[kc], Bf[kc][ntl][1], a2[ntl], 0, 0, 0);
        a1[ntl] = __builtin_amdgcn_mfma_f32_16x16x32_bf16(Ah[kc], Bf[kc][ntl][0], a1[ntl], 0, 0, 0);
      }
    }
    if (layer > 0) {
      #pragma unroll
      for (int kc = 0; kc < 4; ++kc) {
        #pragma unroll
        for (int ntl = 0; ntl < 2; ++ntl) {
          c2[ntl] = __builtin_amdgcn_mfma_f32_16x16x32_bf16(Ai[kc], Bf[kc + 4][ntl][1], c2[ntl], 0, 0, 0);
          c1[ntl] = __builtin_amdgcn_mfma_f32_16x16x32_bf16(Ai[kc], Bf[kc + 4][ntl][0], c1[ntl], 0, 0, 0);
        }
      }
    }

    // ---- epilogue: merge, bias(+x*w0), tanh, pack bf16, write hbuf[nxt] ----
    #pragma unroll
    for (int ntl = 0; ntl < 2; ++ntl) {
      f32x4 sum = (a1[ntl] + a2[ntl]) + (c1[ntl] + c2[ntl]);
      #pragma unroll
      for (int r = 0; r < 4; ++r) {
        const int m = quad * 4 + r;
        float v = sum[r] + br[ntl];
        if (layer == 0) v += xin[par][m] * w0r[ntl];
        float h = fast_tanh(v);
        hreg[ntl][r] = h;
        if (jcv[ntl] < HH) hbuf[nxt][m][jcv[ntl]] = bf_rtn(h);
      }
    }

    if (t == TTS - 1) {   // final hidden state, fp32-exact from registers
      #pragma unroll
      for (int ntl = 0; ntl < 2; ++ntl)
        if (jcv[ntl] < HH)
          #pragma unroll
          for (int r = 0; r < 4; ++r)
            out[(size_t)BBS * TTS +
                ((size_t)layer * BBS + chunk * BC + quad * 4 + r) * HH + jcv[ntl]] =
                hreg[ntl][r];
    }

    // ---- stage prefetched slot t+1 (pA, >=1.5 steps in flight) ----
    if (layer > 0 && !batch_last) {
      *(u32x4*)(inext + co0) = pA0;
      if (tid < 16) *(u32x4*)(inext + co1) = pA1;
      pA0 = pB0; pA1 = pB1;
    }
    if (layer == 0 && t + 1 < TTS && tid < BC) xin[nxt][tid] = px;

    if (batch_last) {
      // slot t must be stored (from fresh hbuf[nxt]) and drained pre-flag
      lds_barrier();           // hbuf[nxt] visible to all waves
      if (layer < NL - 1) {
        char* dstb = (char*)(ring_out + (size_t)(t & RDm) * SLOTB);
        u32x4 a0 = *(const u32x4*)(hnext + co0);
        u32x4 a1v = {};
        if (tid < 16) a1v = *(const u32x4*)(hnext + co1);
        *(u32x4*)(dstb + co0) = a0;
        if (tid < 16) *(u32x4*)(dstb + co1) = a1v;
      }
      __syncthreads();         // full drain: ring stores visible pre-flag
      if (tid == 0) {
        if (layer < NL - 1)
          __hip_atomic_store(prog_out, t + 1, __ATOMIC_RELEASE, __HIP_MEMORY_SCOPE_AGENT);
        if (layer > 0)
          __hip_atomic_store(cons_in, t + 1, __ATOMIC_RELAXED, __HIP_MEMORY_SCOPE_AGENT);
      }
    } else {
      lds_barrier();           // LDS ordered; global stores remain in flight
    }

    // ---- layer-9 output dot (reads fresh hbuf[nxt], reconstruct bf16) ----
    if (layer == NL - 1) {
      const int b = tid >> 4, seg = tid & 15;
      float s = 0.f;
      #pragma unroll
      for (int jj = 0; jj < 7; ++jj) {
        const int j = seg * 7 + jj;
        if (j < HH) {
          float h = __uint_as_float((unsigned)hbuf[nxt][b][j] << 16);
          s += h * wouts[j];
        }
      }
      s += __shfl_xor(s, 1, 16);
      s += __shfl_xor(s, 2, 16);
      s += __shfl_xor(s, 4, 16);
      s += __shfl_xor(s, 8, 16);
      dso = s + boutv;
      if (t < TTS - 1) have_out_def = true;
    }
  }

  // flush last layer-9 outputs (t = TTS-1)
  if (layer == NL - 1 && (tid & 15) == 0)
    out[(size_t)(chunk * BC + (tid >> 4)) * TTS + (TTS - 1)] = dso;
}

extern "C" void kernel_launch(void* const* d_in, const int* in_sizes, int n_in,
                              void* d_out, int out_size, void* d_ws, size_t ws_size,
                              hipStream_t stream) {
  const float* x    = (const float*)d_in[0];
  const float* h0   = (const float*)d_in[1];
  const float* Wih0 = (const float*)d_in[2];
  const float* Wih  = (const float*)d_in[3];
  const float* Whh  = (const float*)d_in[4];
  const float* bih  = (const float*)d_in[5];
  const float* bhh  = (const float*)d_in[6];
  const float* Wout = (const float*)d_in[7];
  const float* bout = (const float*)d_in[8];
  float* out = (float*)d_out;

  int*   wsi  = (int*)d_ws;
  unsigned char* ring = (unsigned char*)d_ws + 65536;

  // bf16 ring: bytes = 9*32 * RD * 4352. RD=32 -> 40.1MB. Deep ring for
  // slack (RD-K = 24 steps), K=8 for short fill (9*8 = 72 steps).
  int RDv = 32;
  while (RDv > 2 && 65536 + (size_t)(NL - 1) * NB * RDv * SLOTB > ws_size)
    RDv >>= 1;
  int Kv = (RDv >= 16) ? 8 : RDv / 2;

  hipLaunchKernelGGL(init_ws_kernel, dim3(64), dim3(256), 0, stream, wsi);
  hipLaunchKernelGGL(rnn_pipe, dim3(NL * NB), dim3(NT), 0, stream,
                     x, h0, Wih0, Wih, Whh, bih, bhh, Wout, bout, out, ring, wsi,
                     Kv, RDv);
}

// Round 6
// 1200.235 us; speedup vs baseline: 1.2292x; 1.2292x over previous
//
#include <hip/hip_runtime.h>

// Multi-layer tanh RNN, layer-pipelined persistent kernel.
// R22 = R21 (layer-pair blocks, NT=512, grid 5x32=160) + DEADLOCK FIX: K=8.
//  R21 hung: with the one-step producer skew (upper computes t=s-1), the
//  batch-last publish of slots <=31 moves to END of block-step 32 while the
//  back-pressure wait (cons >= s+K-RD) stays at START of step 32; the
//  consumer symmetrically publishes cons=16 at its step-16 END but waits
//  prog>=32 at step-16 START -> circular wait. Deadlock-free needs 2K < RD;
//  K=16/RD=32 violated it exactly. K=8/RD=32 gives 16 steps of margin.
// Design (unchanged from R21):
//  - Pair layers (2p, 2p+1) in one 8-wave block: every SIMD hosts one
//    lower-layer wave + one upper-layer wave = two independent dependency
//    chains interleaved uniformly (R19's 1-wave/SIMD CUs were the limiter).
//  - Intra-pair handoff is LDS-direct (upper's input IS lower's hbuf[par]),
//    killing 5 of 9 ring interfaces; fill ~= NIF*K = 32 steps.
//  - 4 cross-pair interfaces keep the R19-proven protocol (fp32 ring,
//    scattered stores, distance-1 prefetch, deferred stores).
// Skew: at block-step s, lower computes t=s (s<TTS), upper t=s-1 (s>=1);
// both read state [par=s&1], write [nxt]. Upper reads lower's h(t-1) from
// hbufL[par], ordered by the shared per-step barrier.

#define HH   100   // hidden
#define HS   132   // padded fp32 stride (bias etc.)
#define HSS  136   // bf16 LDS row stride in shorts (272B = 17*16, b128-aligned)
#define NL   10    // layers
#define NPAIR 5    // layer pairs per chunk
#define NIF   4    // global ring interfaces (between pairs)
#define BBS  512   // batch
#define TTS  512   // time
#define NB   32    // batch chunks
#define BC   16    // batch per chunk
#define NT   512   // threads per block (8 waves: 0-3 lower, 4-7 upper)

typedef __attribute__((ext_vector_type(8))) short short8;
typedef __attribute__((ext_vector_type(4))) float f32x4;
typedef __attribute__((ext_vector_type(2))) unsigned int u32x2;

__global__ void init_ws_kernel(int* wsi) {
  int i = blockIdx.x * blockDim.x + threadIdx.x;
  if (i < 16384) wsi[i] = 0;   // zero both flag regions (64KB)
}

__device__ __forceinline__ int flag_idx(int iface, int chunk) {
  return (iface * NB + chunk) * 16;
}

__device__ __forceinline__ void lds_barrier() {
  __asm__ __volatile__("s_waitcnt lgkmcnt(0)\n\ts_barrier" ::: "memory");
}
__device__ __forceinline__ void ctl_barrier() {
  __asm__ __volatile__("s_barrier" ::: "memory");
}

__device__ __forceinline__ float fast_tanh(float v) {
  float e = __expf(2.0f * v);
  return 1.0f - 2.0f * __builtin_amdgcn_rcpf(e + 1.0f);
}

__device__ __forceinline__ unsigned short bf_rtn(float x) {
  return (unsigned short)((__float_as_uint(x) + 0x8000u) >> 16);
}
__device__ __forceinline__ unsigned pack_rtn(float x0, float x1) {
  unsigned u0 = __float_as_uint(x0) + 0x8000u;
  unsigned u1 = __float_as_uint(x1) + 0x8000u;
  return (u0 >> 16) | (u1 & 0xFFFF0000u);
}
__device__ __forceinline__ u32x2 pack4(f32x4 q) {
  u32x2 d;
  d[0] = pack_rtn(q[0], q[1]);
  d[1] = pack_rtn(q[2], q[3]);
  return d;
}

__global__ __launch_bounds__(NT, 1) void rnn_pipe(
    const float* __restrict__ x,     // [B,T,1]
    const float* __restrict__ h0,    // [L,B,H]
    const float* __restrict__ Wih0,  // [H,1]
    const float* __restrict__ Wih,   // [L-1,H,H]
    const float* __restrict__ Whh,   // [L,H,H]
    const float* __restrict__ bih,   // [L,H]
    const float* __restrict__ bhh,   // [L,H]
    const float* __restrict__ Wout,  // [1,H]
    const float* __restrict__ bout,  // [1]
    float* __restrict__ out,         // [B*T] outs ++ [L*B*H] h_final
    float* __restrict__ ring,
    int*   __restrict__ wsi,
    int Kv, int RDv)
{
  const int pair  = blockIdx.x / NB;
  const int chunk = blockIdx.x % NB;
  const int tid   = threadIdx.x;
  const int grp   = tid >> 8;          // 0 = lower layer (2p), 1 = upper (2p+1)
  const int wtid  = tid & 255;
  const int layer = pair * 2 + grp;
  const int Km = Kv - 1, RDm = RDv - 1;
  const int NE = BC * HH;  // 1600 elements per activation slot

  const int wave = wtid >> 6, lane = wtid & 63;
  const int quad = lane >> 4, lp = lane & 15;

  // LDS: 3 state buffers (26.1KB) + consts (~2.3KB)
  __shared__ unsigned short hbufL[2][BC][HSS];  // lower recurrent state bf16
  __shared__ unsigned short hbufU[2][BC][HSS];  // upper recurrent state bf16
  __shared__ unsigned short ibufL[2][BC][HSS];  // lower ring-staged input bf16
  __shared__ float biasS[2][HS];
  __shared__ float wi0s[HS];
  __shared__ float wouts[HS];
  __shared__ float xin[2][BC];

  // ---- one-time LDS init ----
  for (int i = tid; i < 2 * BC * HSS; i += NT) {
    (&hbufL[0][0][0])[i] = 0; (&hbufU[0][0][0])[i] = 0; (&ibufL[0][0][0])[i] = 0;
  }
  for (int i = wtid; i < HS; i += 256) {
    biasS[grp][i] = (i < HH) ? (bih[layer * HH + i] + bhh[layer * HH + i]) : 0.f;
    if (grp == 0) wi0s[i]  = (i < HH) ? Wih0[i] : 0.f;
    else          wouts[i] = (i < HH) ? Wout[i] : 0.f;
  }
  if (tid < BC) { xin[0][tid] = 0.f; xin[1][tid] = 0.f; }
  __syncthreads();
  // h0: lower reads at s=0 from [par=0]; upper reads at s=1 from [par=1]
  for (int idx = wtid; idx < NE; idx += 256) {
    unsigned short v =
        bf_rtn(h0[((size_t)layer * BBS + chunk * BC + idx / HH) * HH + idx % HH]);
    if (grp == 0) hbufL[0][idx / HH][idx % HH] = v;
    else          hbufU[1][idx / HH][idx % HH] = v;
  }
  __syncthreads();

  // ---- B-fragments: fused W = [Whh (k 0..99) ; Wih (k 128..227)], 2-plane ----
  short8 Bf[8][2][2];
  #pragma unroll
  for (int kc = 0; kc < 8; ++kc) {
    #pragma unroll
    for (int ntl = 0; ntl < 2; ++ntl) {
      const int n = wave * 32 + ntl * 16 + lp;
      float wv[8];
      #pragma unroll
      for (int j = 0; j < 8; ++j) {
        const int k = kc * 32 + quad * 8 + j;
        float w = 0.f;
        if (kc < 4) {
          if (k < HH && n < HH) w = Whh[(size_t)layer * HH * HH + n * HH + k];
        } else {
          const int kk = k - 128;
          if (layer > 0 && kk >= 0 && kk < HH && n < HH)
            w = Wih[(size_t)(layer - 1) * HH * HH + n * HH + kk];
        }
        wv[j] = w;
      }
      __attribute__((ext_vector_type(4))) unsigned int p1, p2;
      #pragma unroll
      for (int j2 = 0; j2 < 4; ++j2) {
        unsigned ua = __float_as_uint(wv[2 * j2]), ub = __float_as_uint(wv[2 * j2 + 1]);
        p1[j2] = (ua >> 16) | (ub & 0xFFFF0000u);
        float ra = wv[2 * j2]     - __uint_as_float(ua & 0xFFFF0000u);
        float rb = wv[2 * j2 + 1] - __uint_as_float(ub & 0xFFFF0000u);
        p2[j2] = (__float_as_uint(ra) >> 16) | (__float_as_uint(rb) & 0xFFFF0000u);
      }
      Bf[kc][ntl][0] = __builtin_bit_cast(short8, p1);
      Bf[kc][ntl][1] = __builtin_bit_cast(short8, p2);
    }
  }

  // ---- flags / ring pointers: 4 cross-pair interfaces, R19 protocol ----
  const bool is_cons = (grp == 0 && pair > 0);            // lower consumes ring
  const bool is_prod = (grp == 1 && pair < NPAIR - 1);    // upper produces ring
  int* prog_in  = is_cons ? wsi + flag_idx(pair - 1, chunk)        : nullptr;
  int* cons_in  = is_cons ? wsi + 8192 + flag_idx(pair - 1, chunk) : nullptr;
  int* prog_out = is_prod ? wsi + flag_idx(pair, chunk)            : nullptr;
  int* cons_out = is_prod ? wsi + 8192 + flag_idx(pair, chunk)     : nullptr;
  const size_t slot_sz = (size_t)NE;  // 1600 floats
  float* ring_in  = is_cons ? ring + (size_t)((pair - 1) * NB + chunk) * RDv * slot_sz : nullptr;
  float* ring_out = is_prod ? ring + (size_t)(pair * NB + chunk) * RDv * slot_sz       : nullptr;

  const int jcv[2] = { wave * 32 + lp, wave * 32 + 16 + lp };   // C columns
  const float br[2]  = { biasS[grp][jcv[0]], biasS[grp][jcv[1]] };
  const float w0r[2] = { wi0s[jcv[0]], wi0s[jcv[1]] };
  const float boutv = bout[0];

  f32x4 hreg[2];             // my h(t) fp32 (deferred stores / h_final)
  float dso = 0.f;           // deferred layer-9 output
  float px = 0.f;
  bool have_ring_def = false, have_out_def = false;

  for (int s = 0; s <= TTS; ++s) {
    const int par = s & 1, nxt = par ^ 1;
    const bool active = (grp == 0) ? (s < TTS) : (s >= 1);
    const int t = (grp == 0) ? s : s - 1;          // my timestep this step
    const bool bstart = (s < TTS) && ((s & Km) == 0);
    const bool upub   = (s >= 1) && ((s & Km) == 0); // upper batch-last steps

    // ---- batch boundary: waits + exposed staging of lower slot s ----
    if (bstart) {
      if (tid == 0 && is_cons) {
        while (__hip_atomic_load(prog_in, __ATOMIC_RELAXED, __HIP_MEMORY_SCOPE_AGENT) < s + Kv)
          __builtin_amdgcn_s_sleep(1);
        (void)__hip_atomic_load(prog_in, __ATOMIC_ACQUIRE, __HIP_MEMORY_SCOPE_AGENT);
      }
      if (tid == 256 && is_prod && s + Kv > RDv) {
        while (__hip_atomic_load(cons_out, __ATOMIC_RELAXED, __HIP_MEMORY_SCOPE_AGENT) < s + Kv - RDv)
          __builtin_amdgcn_s_sleep(1);
      }
      ctl_barrier();
      if (grp == 0) {
        if (pair > 0) {
          const float* src = ring_in + (size_t)(s & RDm) * slot_sz;
          int i0 = wtid * 4;
          if (i0 < NE) {
            u32x2 d = pack4(*(const f32x4*)(src + i0));
            *(u32x2*)&ibufL[par][i0 / HH][i0 % HH] = d;
          }
          int i1 = i0 + 1024;
          if (i1 < NE) {
            u32x2 d = pack4(*(const f32x4*)(src + i1));
            *(u32x2*)&ibufL[par][i1 / HH][i1 % HH] = d;
          }
        } else if (s == 0) {
          if (wtid < BC) xin[0][wtid] = x[(size_t)(chunk * BC + wtid) * TTS];
        }
      }
      lds_barrier();
    }

    // ---- deferred stores from previous step (in flight past barriers) ----
    if (have_ring_def) {   // upper producer: slot s-2 from hreg
      float* dst = ring_out + (size_t)((s - 2) & RDm) * slot_sz;
      #pragma unroll
      for (int ntl = 0; ntl < 2; ++ntl)
        if (jcv[ntl] < HH)
          #pragma unroll
          for (int r = 0; r < 4; ++r)
            dst[(size_t)(quad * 4 + r) * HH + jcv[ntl]] = hreg[ntl][r];
      have_ring_def = false;
    }
    if (have_out_def) {    // layer-9 output for t = s-2
      if ((wtid & 15) == 0)
        out[(size_t)(chunk * BC + (wtid >> 4)) * TTS + (s - 2)] = dso;
      have_out_def = false;
    }

    // ---- prefetch next lower input (ring slot s+1 / x scalar) ----
    f32x4 p0 = {}, p1 = {};
    bool pre = false;
    if (grp == 0 && active) {
      if (pair > 0) {
        if (((s & Km) != Km) && s + 1 < TTS) {
          const float* src = ring_in + (size_t)((s + 1) & RDm) * slot_sz;
          int i0 = wtid * 4;
          if (i0 < NE) p0 = *(const f32x4*)(src + i0);
          if (i0 + 1024 < NE) p1 = *(const f32x4*)(src + i0 + 1024);
          pre = true;
        }
      } else {
        if (s + 1 < TTS && wtid < BC) px = x[(size_t)(chunk * BC + wtid) * TTS + (s + 1)];
      }
    }

    if (active) {
      // ---- A-fragments: hoisted LDS reads ----
      const unsigned short (*myH)[HSS] = (grp == 0) ? hbufL[par] : hbufU[par];
      const unsigned short (*myI)[HSS] = (grp == 0) ? ibufL[par] : hbufL[par];
      short8 Ah[4], Ai[4];
      #pragma unroll
      for (int kc = 0; kc < 4; ++kc)
        Ah[kc] = *(const short8*)&myH[lp][kc * 32 + quad * 8];
      if (layer > 0) {
        #pragma unroll
        for (int kc = 0; kc < 4; ++kc)
          Ai[kc] = *(const short8*)&myI[lp][kc * 32 + quad * 8];
      } else {
        #pragma unroll
        for (int kc = 0; kc < 4; ++kc) Ai[kc] = short8{};
      }

      // ---- MFMA: split per-plane chains (4-deep), merged by VALU adds ----
      f32x4 a1[2] = {}, a2[2] = {};
      f32x4 c1[2] = {}, c2[2] = {};
      #pragma unroll
      for (int kc = 0; kc < 4; ++kc) {
        #pragma unroll
        for (int ntl = 0; ntl < 2; ++ntl) {
          a2[ntl] = __builtin_amdgcn_mfma_f32_16x16x32_bf16(Ah[kc], Bf[kc][ntl][1], a2[ntl], 0, 0, 0);
          a1[ntl] = __builtin_amdgcn_mfma_f32_16x16x32_bf16(Ah[kc], Bf[kc][ntl][0], a1[ntl], 0, 0, 0);
        }
      }
      if (layer > 0) {
        #pragma unroll
        for (int kc = 0; kc < 4; ++kc) {
          #pragma unroll
          for (int ntl = 0; ntl < 2; ++ntl) {
            c2[ntl] = __builtin_amdgcn_mfma_f32_16x16x32_bf16(Ai[kc], Bf[kc + 4][ntl][1], c2[ntl], 0, 0, 0);
            c1[ntl] = __builtin_amdgcn_mfma_f32_16x16x32_bf16(Ai[kc], Bf[kc + 4][ntl][0], c1[ntl], 0, 0, 0);
          }
        }
      }

      // ---- epilogue: merge, bias(+x*w0), tanh, pack bf16, write [nxt] ----
      unsigned short (*myHn)[HSS] = (grp == 0) ? hbufL[nxt] : hbufU[nxt];
      #pragma unroll
      for (int ntl = 0; ntl < 2; ++ntl) {
        f32x4 sum = (a1[ntl] + a2[ntl]) + (c1[ntl] + c2[ntl]);
        #pragma unroll
        for (int r = 0; r < 4; ++r) {
          const int m = quad * 4 + r;
          float v = sum[r] + br[ntl];
          if (layer == 0) v += xin[par][m] * w0r[ntl];
          float h = fast_tanh(v);
          hreg[ntl][r] = h;
          if (jcv[ntl] < HH) myHn[m][jcv[ntl]] = bf_rtn(h);
        }
      }

      // upper batch-last ring store (slot t = s-1), cannot defer past publish
      if (is_prod && upub) {
        float* dst = ring_out + (size_t)((s - 1) & RDm) * slot_sz;
        #pragma unroll
        for (int ntl = 0; ntl < 2; ++ntl)
          if (jcv[ntl] < HH)
            #pragma unroll
            for (int r = 0; r < 4; ++r)
              dst[(size_t)(quad * 4 + r) * HH + jcv[ntl]] = hreg[ntl][r];
      }
      if (t == TTS - 1) {   // final hidden state, fp32-exact from registers
        #pragma unroll
        for (int ntl = 0; ntl < 2; ++ntl)
          if (jcv[ntl] < HH)
            #pragma unroll
            for (int r = 0; r < 4; ++r)
              out[(size_t)BBS * TTS +
                  ((size_t)layer * BBS + chunk * BC + quad * 4 + r) * HH + jcv[ntl]] =
                  hreg[ntl][r];
      }
    }

    // ---- stage prefetched lower input into [nxt] ----
    if (pre) {
      int i0 = wtid * 4;
      if (i0 < NE) *(u32x2*)&ibufL[nxt][i0 / HH][i0 % HH] = pack4(p0);
      int i1 = i0 + 1024;
      if (i1 < NE) *(u32x2*)&ibufL[nxt][i1 / HH][i1 % HH] = pack4(p1);
    }
    if (grp == 0 && pair == 0 && s + 1 < TTS && wtid < BC) xin[nxt][wtid] = px;

    // ---- end-of-step barrier (+ publishes at upper batch-last) ----
    if (upub) {
      __syncthreads();   // full drain: all ring stores visible pre-flag
      if (tid == 256 && is_prod)
        __hip_atomic_store(prog_out, s, __ATOMIC_RELEASE, __HIP_MEMORY_SCOPE_AGENT);
      if (tid == 0 && is_cons)
        __hip_atomic_store(cons_in, s, __ATOMIC_RELAXED, __HIP_MEMORY_SCOPE_AGENT);
    } else {
      lds_barrier();
    }

    // ---- layer-9 output dot (reads fresh hbufU[nxt], reconstruct bf16) ----
    if (grp == 1 && pair == NPAIR - 1 && active) {
      const int b = wtid >> 4, seg = wtid & 15;
      float sacc = 0.f;
      #pragma unroll
      for (int jj = 0; jj < 7; ++jj) {
        const int j = seg * 7 + jj;
        if (j < HH) {
          float h = __uint_as_float((unsigned)hbufU[nxt][b][j] << 16);
          sacc += h * wouts[j];
        }
      }
      sacc += __shfl_xor(sacc, 1, 16);
      sacc += __shfl_xor(sacc, 2, 16);
      sacc += __shfl_xor(sacc, 4, 16);
      sacc += __shfl_xor(sacc, 8, 16);
      dso = sacc + boutv;
      if (t < TTS - 1) have_out_def = true;
    }
    if (is_prod && active && !upub) have_ring_def = true;
  }

  // flush last layer-9 outputs (t = TTS-1)
  if (grp == 1 && pair == NPAIR - 1 && (wtid & 15) == 0)
    out[(size_t)(chunk * BC + (wtid >> 4)) * TTS + (TTS - 1)] = dso;
}

extern "C" void kernel_launch(void* const* d_in, const int* in_sizes, int n_in,
                              void* d_out, int out_size, void* d_ws, size_t ws_size,
                              hipStream_t stream) {
  const float* x    = (const float*)d_in[0];
  const float* h0   = (const float*)d_in[1];
  const float* Wih0 = (const float*)d_in[2];
  const float* Wih  = (const float*)d_in[3];
  const float* Whh  = (const float*)d_in[4];
  const float* bih  = (const float*)d_in[5];
  const float* bhh  = (const float*)d_in[6];
  const float* Wout = (const float*)d_in[7];
  const float* bout = (const float*)d_in[8];
  float* out = (float*)d_out;

  int*   wsi  = (int*)d_ws;
  float* ring = (float*)((char*)d_ws + 65536);

  // 4 interfaces only: ring bytes = 4*32 * RD * 6400 (RD=32 -> 26.2MB).
  const size_t slot_bytes = (size_t)BC * HH * 4;   // 6400
  int RDv = 32;
  while (RDv > 2 && 65536 + (size_t)NIF * NB * RDv * slot_bytes > ws_size)
    RDv >>= 1;
  // DEADLOCK-FREE: skewed pipeline needs 2K < RD (see header). K = RD/4.
  int Kv = RDv / 4;
  if (Kv < 1) Kv = 1;

  hipLaunchKernelGGL(init_ws_kernel, dim3(64), dim3(256), 0, stream, wsi);
  hipLaunchKernelGGL(rnn_pipe, dim3(NPAIR * NB), dim3(NT), 0, stream,
                     x, h0, Wih0, Wih, Whh, bih, bhh, Wout, bout, out, ring, wsi,
                     Kv, RDv);
}

// Round 7
// 1108.192 us; speedup vs baseline: 1.3313x; 1.0831x over previous
//
#include <hip/hip_runtime.h>

// Multi-layer tanh RNN, layer-pipelined persistent kernel.
// R23 = R22 (layer-pair blocks, NT=512, K=8/RD=32, 1200us) + step-wall diet:
//  (a) j-major bf16 ring: producer stores its hreg as packed bf16 at
//      [j][m] -> one dwordx2 per lane, 1KB dense per wave (was 8 scattered
//      dwords/lane = ~64 lines/instr, ~1000cyc of VMEM TA per CU-step).
//      Consumer stages via 8 scattered ds_write_b16 (+~100cyc LDS, -pack4
//      VALU). Ring values = RTN-bf16 of the same fp32 h the consumer used
//      to round anyway -> ibufL contents BIT-IDENTICAL to R22.
//  (b) layer-9 dot folded into MFMA: n-columns 100..127 were wasted; set
//      col 100 weights = Wout (2-plane exact) and bias = bout. The step-s
//      MFMA then yields h9(s-2)*wout = out(s-2) for free, matching the old
//      deferred-out schedule; kills the post-barrier serial dot (7 LDS
//      reads + shfl chain) on the pace-setting last stage. out(T-1) via one
//      post-loop serial dot.
//  R22 analysis: step wall 2.15us unchanged from R16; win was all fill.
//  512*2.15 = 1100us is this structure's zero-fill bound; step-wall cuts
//  are the only lever left. Budget: LDS ~1150cyc, VALU ~1100, VMEM-TA
//  ~1000 (scattered ring stores!), MFMA ~615, 2 barriers.

#define HH   100   // hidden
#define HS   132   // padded fp32 stride (bias etc.)
#define HSS  136   // bf16 LDS row stride in shorts (272B = 17*16, b128-aligned)
#define NL   10    // layers
#define NPAIR 5    // layer pairs per chunk
#define NIF   4    // global ring interfaces (between pairs)
#define BBS  512   // batch
#define TTS  512   // time
#define NB   32    // batch chunks
#define BC   16    // batch per chunk
#define NT   512   // threads per block (8 waves: 0-3 lower, 4-7 upper)
#define SLOTS (HH * BC)        // ring slot size in shorts (1600 = 3200B)

typedef __attribute__((ext_vector_type(8))) short short8;
typedef __attribute__((ext_vector_type(4))) float f32x4;
typedef __attribute__((ext_vector_type(2))) unsigned int u32x2;
typedef __attribute__((ext_vector_type(4))) unsigned int u32x4;

__global__ void init_ws_kernel(int* wsi) {
  int i = blockIdx.x * blockDim.x + threadIdx.x;
  if (i < 16384) wsi[i] = 0;   // zero both flag regions (64KB)
}

__device__ __forceinline__ int flag_idx(int iface, int chunk) {
  return (iface * NB + chunk) * 16;
}

__device__ __forceinline__ void lds_barrier() {
  __asm__ __volatile__("s_waitcnt lgkmcnt(0)\n\ts_barrier" ::: "memory");
}
__device__ __forceinline__ void ctl_barrier() {
  __asm__ __volatile__("s_barrier" ::: "memory");
}

__device__ __forceinline__ float fast_tanh(float v) {
  float e = __expf(2.0f * v);
  return 1.0f - 2.0f * __builtin_amdgcn_rcpf(e + 1.0f);
}

__device__ __forceinline__ unsigned short bf_rtn(float x) {
  return (unsigned short)((__float_as_uint(x) + 0x8000u) >> 16);
}
__device__ __forceinline__ unsigned pack_rtn(float x0, float x1) {
  unsigned u0 = __float_as_uint(x0) + 0x8000u;
  unsigned u1 = __float_as_uint(x1) + 0x8000u;
  return (u0 >> 16) | (u1 & 0xFFFF0000u);
}

__global__ __launch_bounds__(NT, 1) void rnn_pipe(
    const float* __restrict__ x,     // [B,T,1]
    const float* __restrict__ h0,    // [L,B,H]
    const float* __restrict__ Wih0,  // [H,1]
    const float* __restrict__ Wih,   // [L-1,H,H]
    const float* __restrict__ Whh,   // [L,H,H]
    const float* __restrict__ bih,   // [L,H]
    const float* __restrict__ bhh,   // [L,H]
    const float* __restrict__ Wout,  // [1,H]
    const float* __restrict__ bout,  // [1]
    float* __restrict__ out,         // [B*T] outs ++ [L*B*H] h_final
    unsigned short* __restrict__ ring,
    int*   __restrict__ wsi,
    int Kv, int RDv)
{
  const int pair  = blockIdx.x / NB;
  const int chunk = blockIdx.x % NB;
  const int tid   = threadIdx.x;
  const int grp   = tid >> 8;          // 0 = lower layer (2p), 1 = upper (2p+1)
  const int wtid  = tid & 255;
  const int layer = pair * 2 + grp;
  const int Km = Kv - 1, RDm = RDv - 1;
  const int NE = BC * HH;  // 1600 elements per activation slot

  const int wave = wtid >> 6, lane = wtid & 63;
  const int quad = lane >> 4, lp = lane & 15;
  const bool is_l9 = (grp == 1 && pair == NPAIR - 1);

  // LDS: 3 state buffers (26.1KB) + consts (~2.3KB)
  __shared__ unsigned short hbufL[2][BC][HSS];  // lower recurrent state bf16
  __shared__ unsigned short hbufU[2][BC][HSS];  // upper recurrent state bf16
  __shared__ unsigned short ibufL[2][BC][HSS];  // lower ring-staged input bf16
  __shared__ float biasS[2][HS];
  __shared__ float wi0s[HS];
  __shared__ float wouts[HS];
  __shared__ float xin[2][BC];

  // ---- one-time LDS init ----
  for (int i = tid; i < 2 * BC * HSS; i += NT) {
    (&hbufL[0][0][0])[i] = 0; (&hbufU[0][0][0])[i] = 0; (&ibufL[0][0][0])[i] = 0;
  }
  for (int i = wtid; i < HS; i += 256) {
    float bv = 0.f;
    if (i < HH) bv = bih[layer * HH + i] + bhh[layer * HH + i];
    else if (i == 100 && layer == NL - 1) bv = bout[0];   // (b) col-100 bias
    biasS[grp][i] = bv;
    if (grp == 0) wi0s[i]  = (i < HH) ? Wih0[i] : 0.f;
    else          wouts[i] = (i < HH) ? Wout[i] : 0.f;
  }
  if (tid < BC) { xin[0][tid] = 0.f; xin[1][tid] = 0.f; }
  __syncthreads();
  // h0: lower reads at s=0 from [par=0]; upper reads at s=1 from [par=1]
  for (int idx = wtid; idx < NE; idx += 256) {
    unsigned short v =
        bf_rtn(h0[((size_t)layer * BBS + chunk * BC + idx / HH) * HH + idx % HH]);
    if (grp == 0) hbufL[0][idx / HH][idx % HH] = v;
    else          hbufU[1][idx / HH][idx % HH] = v;
  }
  __syncthreads();

  // ---- B-fragments: fused W = [Whh (k 0..99) ; Wih (k 128..227)], 2-plane.
  // (b): for layer 9, n==100 carries Wout in the Whh half (c-half stays 0).
  short8 Bf[8][2][2];
  #pragma unroll
  for (int kc = 0; kc < 8; ++kc) {
    #pragma unroll
    for (int ntl = 0; ntl < 2; ++ntl) {
      const int n = wave * 32 + ntl * 16 + lp;
      float wv[8];
      #pragma unroll
      for (int j = 0; j < 8; ++j) {
        const int k = kc * 32 + quad * 8 + j;
        float w = 0.f;
        if (kc < 4) {
          if (k < HH) {
            if (n < HH) w = Whh[(size_t)layer * HH * HH + n * HH + k];
            else if (n == 100 && layer == NL - 1) w = Wout[k];
          }
        } else {
          const int kk = k - 128;
          if (layer > 0 && kk >= 0 && kk < HH && n < HH)
            w = Wih[(size_t)(layer - 1) * HH * HH + n * HH + kk];
        }
        wv[j] = w;
      }
      __attribute__((ext_vector_type(4))) unsigned int p1, p2;
      #pragma unroll
      for (int j2 = 0; j2 < 4; ++j2) {
        unsigned ua = __float_as_uint(wv[2 * j2]), ub = __float_as_uint(wv[2 * j2 + 1]);
        p1[j2] = (ua >> 16) | (ub & 0xFFFF0000u);
        float ra = wv[2 * j2]     - __uint_as_float(ua & 0xFFFF0000u);
        float rb = wv[2 * j2 + 1] - __uint_as_float(ub & 0xFFFF0000u);
        p2[j2] = (__float_as_uint(ra) >> 16) | (__float_as_uint(rb) & 0xFFFF0000u);
      }
      Bf[kc][ntl][0] = __builtin_bit_cast(short8, p1);
      Bf[kc][ntl][1] = __builtin_bit_cast(short8, p2);
    }
  }

  // ---- flags / ring pointers: 4 cross-pair interfaces, R19 protocol ----
  const bool is_cons = (grp == 0 && pair > 0);            // lower consumes ring
  const bool is_prod = (grp == 1 && pair < NPAIR - 1);    // upper produces ring
  int* prog_in  = is_cons ? wsi + flag_idx(pair - 1, chunk)        : nullptr;
  int* cons_in  = is_cons ? wsi + 8192 + flag_idx(pair - 1, chunk) : nullptr;
  int* prog_out = is_prod ? wsi + flag_idx(pair, chunk)            : nullptr;
  int* cons_out = is_prod ? wsi + 8192 + flag_idx(pair, chunk)     : nullptr;
  unsigned short* ring_in  = is_cons ? ring + (size_t)((pair - 1) * NB + chunk) * RDv * SLOTS : nullptr;
  unsigned short* ring_out = is_prod ? ring + (size_t)(pair * NB + chunk) * RDv * SLOTS       : nullptr;

  const int jcv[2] = { wave * 32 + lp, wave * 32 + 16 + lp };   // C columns
  const float br[2]  = { biasS[grp][jcv[0]], biasS[grp][jcv[1]] };
  const float w0r[2] = { wi0s[jcv[0]], wi0s[jcv[1]] };
  const float boutv = bout[0];

  f32x4 hreg[2] = {};        // my h(t) fp32 (deferred stores / h_final)
  float px = 0.f;
  bool have_ring_def = false;

  for (int s = 0; s <= TTS; ++s) {
    const int par = s & 1, nxt = par ^ 1;
    const bool active = (grp == 0) ? (s < TTS) : (s >= 1);
    const int t = (grp == 0) ? s : s - 1;          // my timestep this step
    const bool bstart = (s < TTS) && ((s & Km) == 0);
    const bool upub   = (s >= 1) && ((s & Km) == 0); // upper batch-last steps

    // ---- batch boundary: waits + exposed staging of lower slot s ----
    if (bstart) {
      if (tid == 0 && is_cons) {
        while (__hip_atomic_load(prog_in, __ATOMIC_RELAXED, __HIP_MEMORY_SCOPE_AGENT) < s + Kv)
          __builtin_amdgcn_s_sleep(1);
        (void)__hip_atomic_load(prog_in, __ATOMIC_ACQUIRE, __HIP_MEMORY_SCOPE_AGENT);
      }
      if (tid == 256 && is_prod && s + Kv > RDv) {
        while (__hip_atomic_load(cons_out, __ATOMIC_RELAXED, __HIP_MEMORY_SCOPE_AGENT) < s + Kv - RDv)
          __builtin_amdgcn_s_sleep(1);
      }
      ctl_barrier();
      if (grp == 0) {
        if (pair > 0) {
          const unsigned int* srcu =
              (const unsigned int*)(ring_in + (size_t)(s & RDm) * SLOTS);
          if (wtid < 200) {
            u32x4 g = *(const u32x4*)(srcu + wtid * 4);
            const int j = wtid >> 1, m0 = (wtid & 1) * 8;
            #pragma unroll
            for (int e = 0; e < 8; ++e) {
              unsigned u = g[e >> 1];
              ibufL[par][m0 + e][j] = (unsigned short)((e & 1) ? (u >> 16) : (u & 0xFFFFu));
            }
          }
        } else if (s == 0) {
          if (wtid < BC) xin[0][wtid] = x[(size_t)(chunk * BC + wtid) * TTS];
        }
      }
      lds_barrier();
    }

    // ---- deferred ring store from previous step (coalesced bf16 j-major) ----
    if (have_ring_def) {   // upper producer: slot s-2 from hreg
      unsigned short* slotp = ring_out + (size_t)((s - 2) & RDm) * SLOTS;
      #pragma unroll
      for (int ntl = 0; ntl < 2; ++ntl) {
        const int j = jcv[ntl];
        if (j < HH) {
          u32x2 d;
          d[0] = pack_rtn(hreg[ntl][0], hreg[ntl][1]);
          d[1] = pack_rtn(hreg[ntl][2], hreg[ntl][3]);
          *(u32x2*)(slotp + j * BC + quad * 4) = d;
        }
      }
      have_ring_def = false;
    }

    // ---- prefetch next lower input (ring slot s+1 / x scalar) ----
    u32x4 pv = {};
    bool pre = false;
    if (grp == 0 && active) {
      if (pair > 0) {
        if (((s & Km) != Km) && s + 1 < TTS && wtid < 200) {
          const unsigned int* srcu =
              (const unsigned int*)(ring_in + (size_t)((s + 1) & RDm) * SLOTS);
          pv = *(const u32x4*)(srcu + wtid * 4);
          pre = true;
        }
      } else {
        if (s + 1 < TTS && wtid < BC) px = x[(size_t)(chunk * BC + wtid) * TTS + (s + 1)];
      }
    }

    if (active) {
      // ---- A-fragments: hoisted LDS reads ----
      const unsigned short (*myH)[HSS] = (grp == 0) ? hbufL[par] : hbufU[par];
      const unsigned short (*myI)[HSS] = (grp == 0) ? ibufL[par] : hbufL[par];
      short8 Ah[4], Ai[4];
      #pragma unroll
      for (int kc = 0; kc < 4; ++kc)
        Ah[kc] = *(const short8*)&myH[lp][kc * 32 + quad * 8];
      if (layer > 0) {
        #pragma unroll
        for (int kc = 0; kc < 4; ++kc)
          Ai[kc] = *(const short8*)&myI[lp][kc * 32 + quad * 8];
      } else {
        #pragma unroll
        for (int kc = 0; kc < 4; ++kc) Ai[kc] = short8{};
      }

      // ---- MFMA: split per-plane chains (4-deep), merged by VALU adds ----
      f32x4 a1[2] = {}, a2[2] = {};
      f32x4 c1[2] = {}, c2[2] = {};
      #pragma unroll
      for (int kc = 0; kc < 4; ++kc) {
        #pragma unroll
        for (int ntl = 0; ntl < 2; ++ntl) {
          a2[ntl] = __builtin_amdgcn_mfma_f32_16x16x32_bf16(Ah[kc], Bf[kc][ntl][1], a2[ntl], 0, 0, 0);
          a1[ntl] = __builtin_amdgcn_mfma_f32_16x16x32_bf16(Ah[kc], Bf[kc][ntl][0], a1[ntl], 0, 0, 0);
        }
      }
      if (layer > 0) {
        #pragma unroll
        for (int kc = 0; kc < 4; ++kc) {
          #pragma unroll
          for (int ntl = 0; ntl < 2; ++ntl) {
            c2[ntl] = __builtin_amdgcn_mfma_f32_16x16x32_bf16(Ai[kc], Bf[kc + 4][ntl][1], c2[ntl], 0, 0, 0);
            c1[ntl] = __builtin_amdgcn_mfma_f32_16x16x32_bf16(Ai[kc], Bf[kc + 4][ntl][0], c1[ntl], 0, 0, 0);
          }
        }
      }

      // ---- epilogue: merge, bias(+x*w0), tanh, pack bf16, write [nxt].
      //      (b): layer-9 column 100 = out(s-2), stored directly (no tanh).
      unsigned short (*myHn)[HSS] = (grp == 0) ? hbufL[nxt] : hbufU[nxt];
      #pragma unroll
      for (int ntl = 0; ntl < 2; ++ntl) {
        f32x4 sum = (a1[ntl] + a2[ntl]) + (c1[ntl] + c2[ntl]);
        #pragma unroll
        for (int r = 0; r < 4; ++r) {
          const int m = quad * 4 + r;
          float v = sum[r] + br[ntl];
          if (layer == 0) v += xin[par][m] * w0r[ntl];
          if (is_l9 && jcv[ntl] == 100) {
            if (s >= 2)
              out[(size_t)(chunk * BC + m) * TTS + (s - 2)] = v;  // br==bout
          } else {
            float h = fast_tanh(v);
            hreg[ntl][r] = h;
            if (jcv[ntl] < HH) myHn[m][jcv[ntl]] = bf_rtn(h);
          }
        }
      }

      // upper batch-last ring store (slot t = s-1), cannot defer past publish
      if (is_prod && upub) {
        unsigned short* slotp = ring_out + (size_t)((s - 1) & RDm) * SLOTS;
        #pragma unroll
        for (int ntl = 0; ntl < 2; ++ntl) {
          const int j = jcv[ntl];
          if (j < HH) {
            u32x2 d;
            d[0] = pack_rtn(hreg[ntl][0], hreg[ntl][1]);
            d[1] = pack_rtn(hreg[ntl][2], hreg[ntl][3]);
            *(u32x2*)(slotp + j * BC + quad * 4) = d;
          }
        }
      }
      if (t == TTS - 1) {   // final hidden state, fp32-exact from registers
        #pragma unroll
        for (int ntl = 0; ntl < 2; ++ntl)
          if (jcv[ntl] < HH)
            #pragma unroll
            for (int r = 0; r < 4; ++r)
              out[(size_t)BBS * TTS +
                  ((size_t)layer * BBS + chunk * BC + quad * 4 + r) * HH + jcv[ntl]] =
                  hreg[ntl][r];
      }
    }

    // ---- stage prefetched lower input into [nxt] ----
    if (pre) {
      const int j = wtid >> 1, m0 = (wtid & 1) * 8;
      #pragma unroll
      for (int e = 0; e < 8; ++e) {
        unsigned u = pv[e >> 1];
        ibufL[nxt][m0 + e][j] = (unsigned short)((e & 1) ? (u >> 16) : (u & 0xFFFFu));
      }
    }
    if (grp == 0 && pair == 0 && s + 1 < TTS && wtid < BC) xin[nxt][wtid] = px;

    // ---- end-of-step barrier (+ publishes at upper batch-last) ----
    if (upub) {
      __syncthreads();   // full drain: all ring stores visible pre-flag
      if (tid == 256 && is_prod)
        __hip_atomic_store(prog_out, s, __ATOMIC_RELEASE, __HIP_MEMORY_SCOPE_AGENT);
      if (tid == 0 && is_cons)
        __hip_atomic_store(cons_in, s, __ATOMIC_RELAXED, __HIP_MEMORY_SCOPE_AGENT);
    } else {
      lds_barrier();
    }

    if (is_prod && active && !upub) have_ring_def = true;
  }

  // final output out(TTS-1) = h9(TTS-1)·wout + bout: one-time serial dot
  // (h9(TTS-1) was written to hbufU[1] at s=TTS; ordered by the s=TTS barrier)
  if (is_l9) {
    const int b = wtid >> 4, seg = wtid & 15;
    float sacc = 0.f;
    #pragma unroll
    for (int jj = 0; jj < 7; ++jj) {
      const int j = seg * 7 + jj;
      if (j < HH) {
        float h = __uint_as_float((unsigned)hbufU[1][b][j] << 16);
        sacc += h * wouts[j];
      }
    }
    sacc += __shfl_xor(sacc, 1, 16);
    sacc += __shfl_xor(sacc, 2, 16);
    sacc += __shfl_xor(sacc, 4, 16);
    sacc += __shfl_xor(sacc, 8, 16);
    if ((wtid & 15) == 0)
      out[(size_t)(chunk * BC + b) * TTS + (TTS - 1)] = sacc + boutv;
  }
}

extern "C" void kernel_launch(void* const* d_in, const int* in_sizes, int n_in,
                              void* d_out, int out_size, void* d_ws, size_t ws_size,
                              hipStream_t stream) {
  const float* x    = (const float*)d_in[0];
  const float* h0   = (const float*)d_in[1];
  const float* Wih0 = (const float*)d_in[2];
  const float* Wih  = (const float*)d_in[3];
  const float* Whh  = (const float*)d_in[4];
  const float* bih  = (const float*)d_in[5];
  const float* bhh  = (const float*)d_in[6];
  const float* Wout = (const float*)d_in[7];
  const float* bout = (const float*)d_in[8];
  float* out = (float*)d_out;

  int* wsi = (int*)d_ws;
  unsigned short* ring = (unsigned short*)((char*)d_ws + 65536);

  // bf16 j-major ring: bytes = 4*32 * RD * 3200 (RD=32 -> 13.1MB).
  const size_t slot_bytes = (size_t)HH * BC * 2;   // 3200
  int RDv = 32;
  while (RDv > 2 && 65536 + (size_t)NIF * NB * RDv * slot_bytes > ws_size)
    RDv >>= 1;
  // DEADLOCK-FREE: skewed pipeline needs 2K < RD. K = RD/4.
  int Kv = RDv / 4;
  if (Kv < 1) Kv = 1;

  hipLaunchKernelGGL(init_ws_kernel, dim3(64), dim3(256), 0, stream, wsi);
  hipLaunchKernelGGL(rnn_pipe, dim3(NPAIR * NB), dim3(NT), 0, stream,
                     x, h0, Wih0, Wih, Whh, bih, bhh, Wout, bout, out, ring, wsi,
                     Kv, RDv);
}